// Round 9
// baseline (588.666 us; speedup 1.0000x reference)
//
#include <hip/hip_runtime.h>
#include <hip/hip_bf16.h>

#define DEVI __device__ __forceinline__

typedef __attribute__((ext_vector_type(8))) short bf16x8;
typedef __attribute__((ext_vector_type(4))) float f32x4;
typedef unsigned short u16;

static constexpr float SCALE = 0.03125f;             // 1/sqrt(1024)
static constexpr float C2 = 0.045084220045134115f;   // SCALE * log2(e)

// fast RNE f32->bf16 (no NaN path; all values finite here)
DEVI u16 f2bf_rne(float f){
    unsigned t = __builtin_bit_cast(unsigned, f);
    t += 0x7fffu + ((t >> 16) & 1u);
    return (u16)(t >> 16);
}
// RNE pack of two f32 -> u32. NOTE: v_cvt_pk_bf16_f32 is RTZ on gfx950 (R3: coherent -2e-3 bias).
DEVI unsigned pack_bf16_rne(float lo, float hi){
    return (unsigned)f2bf_rne(lo) | ((unsigned)f2bf_rne(hi) << 16);
}
// POSITIVE-ONLY round-half-up pack: +half-ulp on bits, then RTZ cvt_pk == RNE (mod exact ties).
DEVI unsigned pack_bf16_pos_rhu(float lo, float hi){
    float a = __builtin_bit_cast(float, __builtin_bit_cast(unsigned, lo) + 0x8000u);
    float b = __builtin_bit_cast(float, __builtin_bit_cast(unsigned, hi) + 0x8000u);
    unsigned r;
    asm("v_cvt_pk_bf16_f32 %0, %1, %2" : "=v"(r) : "v"(a), "v"(b));
    return r;
}
DEVI float exp2_hw(float x){
#if defined(__has_builtin) && __has_builtin(__builtin_amdgcn_exp2f)
    return __builtin_amdgcn_exp2f(x);
#else
    return __expf(x * 0.6931471805599453f);
#endif
}

DEVI void gload16(const void* g, void* l){
    __builtin_amdgcn_global_load_lds(
        (const __attribute__((address_space(1))) void*)g,
        (__attribute__((address_space(3))) void*)l,
        16, 0, 0);
}

DEVI void plswap32(unsigned &a, unsigned &b){
#if defined(__has_builtin) && __has_builtin(__builtin_amdgcn_permlane32_swap)
    typedef unsigned uv2 __attribute__((ext_vector_type(2)));
    uv2 r = __builtin_amdgcn_permlane32_swap(a, b, false, false);
    a = r[0]; b = r[1];
#else
    asm("v_permlane32_swap_b32 %0, %1" : "+v"(a), "+v"(b));
#endif
}
DEVI void plswap16(unsigned &a, unsigned &b){
#if defined(__has_builtin) && __has_builtin(__builtin_amdgcn_permlane16_swap)
    typedef unsigned uv2 __attribute__((ext_vector_type(2)));
    uv2 r = __builtin_amdgcn_permlane16_swap(a, b, false, false);
    a = r[0]; b = r[1];
#else
    asm("v_permlane16_swap_b32 %0, %1" : "+v"(a), "+v"(b));
#endif
}

// ---------------- fp32 -> bf16 bulk convert ----------------
__global__ __launch_bounds__(256) void k_cvt(const float* __restrict__ src,
                                             u16* __restrict__ dst, int n8){
    int stride = gridDim.x * blockDim.x;
    for (int i = blockIdx.x * blockDim.x + threadIdx.x; i < n8; i += stride){
        float4 a = *(const float4*)(src + (size_t)i*8);
        float4 b = *(const float4*)(src + (size_t)i*8 + 4);
        uint4 o;
        o.x = pack_bf16_rne(a.x, a.y);
        o.y = pack_bf16_rne(a.z, a.w);
        o.z = pack_bf16_rne(b.x, b.y);
        o.w = pack_bf16_rne(b.z, b.w);
        *(uint4*)(dst + (size_t)i*8) = o;
    }
}

// ---------------- 128x128 NT GEMM, C = A * B^T ----------------
// EPI 0: fp32 store. EPI 1: QKV scatter -> qh (pre-scaled by C2) / kh + vT (transposed, packed).
template<int EPI>
__global__ __launch_bounds__(256) void k_gemm(
    const u16* __restrict__ A, const u16* __restrict__ Bm,
    float* __restrict__ Cf, u16* __restrict__ qh, u16* __restrict__ kh, u16* __restrict__ vT,
    int K, int N)
{
    __shared__ __align__(16) u16 As[128*32];
    __shared__ __align__(16) u16 Bs[128*32];
    const int lane = threadIdx.x & 63, wid = threadIdx.x >> 6;

    const int nbx = gridDim.x;
    const int nwg = nbx * gridDim.y;
    const int bid = blockIdx.y * nbx + blockIdx.x;
    const int swz = (bid & 7) * (nwg >> 3) + (bid >> 3);
    const int rowTile = (swz / nbx) * 128;
    const int colTile = (swz % nbx) * 128;

    const int wr = wid >> 1, wc = wid & 1;
    const int lrow = lane >> 2, lch = lane & 3;

    f32x4 acc[4][4] = {};

    for (int k0 = 0; k0 < K; k0 += 32){
        __syncthreads();
        #pragma unroll
        for (int cc = 0; cc < 2; ++cc){
            int c = wid*2 + cc;
            int row = c*16 + lrow;
            gload16(A + (size_t)(rowTile + row)*K + k0 + lch*8, (char*)As + c*1024);
            gload16(Bm + (size_t)(colTile + row)*K + k0 + lch*8, (char*)Bs + c*1024);
        }
        __syncthreads();
        bf16x8 af[4], bfr[4];
        #pragma unroll
        for (int mi = 0; mi < 4; ++mi){
            int row = wr*64 + mi*16 + (lane & 15);
            af[mi] = *(const bf16x8*)((const char*)As + row*64 + (lane>>4)*16);
        }
        #pragma unroll
        for (int nj = 0; nj < 4; ++nj){
            int row = wc*64 + nj*16 + (lane & 15);
            bfr[nj] = *(const bf16x8*)((const char*)Bs + row*64 + (lane>>4)*16);
        }
        #pragma unroll
        for (int mi = 0; mi < 4; ++mi)
            #pragma unroll
            for (int nj = 0; nj < 4; ++nj)
                acc[mi][nj] = __builtin_amdgcn_mfma_f32_16x16x32_bf16(af[mi], bfr[nj], acc[mi][nj], 0,0,0);
    }

    #pragma unroll
    for (int mi = 0; mi < 4; ++mi)
        #pragma unroll
        for (int nj = 0; nj < 4; ++nj){
            int row0 = rowTile + wr*64 + mi*16 + (lane>>4)*4;
            int col  = colTile + wc*64 + nj*16 + (lane & 15);
            if (EPI == 0){
                #pragma unroll
                for (int j = 0; j < 4; ++j)
                    Cf[(size_t)(row0+j)*N + col] = acc[mi][nj][j];
            } else {
                int b = row0 >> 11, srow0 = row0 & 2047;
                if (col < 2048){
                    // q gets pre-scaled by C2 so attention passes do exp2(z) with no mul
                    bool isq = (col < 1024);
                    u16* dst = isq ? qh : kh;
                    float scl = isq ? C2 : 1.0f;
                    int c2 = col & 1023; int h = c2 >> 6, dh = c2 & 63;
                    size_t base = ((size_t)((b<<4)+h)*2048 + srow0)*64 + dh;
                    #pragma unroll
                    for (int j = 0; j < 4; ++j)
                        dst[base + (size_t)j*64] = f2bf_rne(acc[mi][nj][j] * scl);
                } else {
                    int c2 = col - 2048; int h = c2 >> 6, dh = c2 & 63;
                    union { u16 s[4]; uint2 u; } p;
                    #pragma unroll
                    for (int j = 0; j < 4; ++j) p.s[j] = f2bf_rne(acc[mi][nj][j]);
                    *(uint2*)(vT + ((size_t)((b<<4)+h)*64 + dh)*2048 + srow0) = p.u;
                }
            }
        }
}

// ---------------- Pass A+V: Z[k] = sum_q exp2(k.qC2); then vT *= 1/Z in place ----------------
// grid (64 bh, 16 kb) -> all blocks of a head land on one XCD (bid%8 = bh%8): Q L2-resident.
// NO LDS staging: all MFMA fragments read direct from global (each inst = 16 rows x full 64B line).
// Wave w owns k rows [w*32, w*32+32).
__global__ __launch_bounds__(256, 4) void k_passAV(
    const u16* __restrict__ qh, const u16* __restrict__ kh, u16* __restrict__ vT)
{
    __shared__ float rz_lds[128];
    const int lane = threadIdx.x & 63, wid = threadIdx.x >> 6;
    const int bh = blockIdx.x, kb = blockIdx.y;
    const int r15 = lane & 15, ch = lane >> 4;

    const u16* khb = kh + ((size_t)bh*2048 + kb*128)*64;
    const u16* qhb = qh + (size_t)bh*2048*64;

    // hoist K fragments (persistent across all q-tiles)
    bf16x8 ak[2][2];
    #pragma unroll
    for (int mi = 0; mi < 2; ++mi)
        #pragma unroll
        for (int kk = 0; kk < 2; ++kk){
            int row = wid*32 + mi*16 + r15;
            ak[mi][kk] = *(const bf16x8*)(khb + (size_t)row*64 + kk*32 + ch*8);
        }

    f32x4 sums[2] = {};
    for (int qt = 0; qt < 16; ++qt){
        #pragma unroll
        for (int nj = 0; nj < 8; ++nj){
            const u16* qrow = qhb + (size_t)(qt*128 + nj*16 + r15)*64;
            bf16x8 bq0 = *(const bf16x8*)(qrow + ch*8);
            bf16x8 bq1 = *(const bf16x8*)(qrow + 32 + ch*8);
            #pragma unroll
            for (int mi = 0; mi < 2; ++mi){
                f32x4 z = {};
                z = __builtin_amdgcn_mfma_f32_16x16x32_bf16(ak[mi][0], bq0, z, 0,0,0);
                z = __builtin_amdgcn_mfma_f32_16x16x32_bf16(ak[mi][1], bq1, z, 0,0,0);
                #pragma unroll
                for (int j = 0; j < 4; ++j) sums[mi][j] += exp2_hw(z[j]);   // q pre-scaled by C2
            }
        }
    }

    // per-k reciprocal denominators -> LDS
    #pragma unroll
    for (int mi = 0; mi < 2; ++mi)
        #pragma unroll
        for (int j = 0; j < 4; ++j){
            float v = sums[mi][j];
            v += __shfl_xor(v, 1); v += __shfl_xor(v, 2);
            v += __shfl_xor(v, 4); v += __shfl_xor(v, 8);
            if ((lane & 15) == 0)
                rz_lds[wid*32 + mi*16 + (lane>>4)*4 + j] = 1.0f / v;
        }
    __syncthreads();

    // scale this block's vT stripe [64 d][128 k] in place (direct global, coalesced 64B/d-row)
    #pragma unroll
    for (int r = 0; r < 4; ++r){
        int ci = r*256 + threadIdx.x;       // 1024 chunks of 16B
        int d = ci >> 4, c = ci & 15;
        u16* vp = vT + ((size_t)bh*64 + d)*2048 + kb*128 + c*8;
        union { uint4 v; unsigned w[4]; } t;
        t.v = *(const uint4*)vp;
        #pragma unroll
        for (int m = 0; m < 4; ++m){
            float2 rzp = *(const float2*)&rz_lds[c*8 + m*2];
            float lo = __builtin_bit_cast(float, t.w[m] << 16) * rzp.x;
            float hi = __builtin_bit_cast(float, t.w[m] & 0xffff0000u) * rzp.y;
            t.w[m] = pack_bf16_rne(lo, hi);   // signed values: keep exact RNE here
        }
        *(uint4*)vp = t.v;
    }
}

// ---------------- Pass B: out[q,d] = sum_k exp2(qC2.k) * (v/Z)[k,d] ----------------
// grid (64 bh, 16 qb): head-per-XCD -> K/V L2-resident. NO LDS, NO barriers: all fragments
// direct from global. Swapped QK^T -> P assembled into PV A-frags in-register via permlanes.
__global__ __launch_bounds__(256, 4) void k_passB(
    const u16* __restrict__ qh, const u16* __restrict__ kh, const u16* __restrict__ vT,
    u16* __restrict__ Zbf)
{
    const int lane = threadIdx.x & 63, wid = threadIdx.x >> 6;
    const int bh = blockIdx.x, qb = blockIdx.y;
    const int r15 = lane & 15, ch = lane >> 4;

    const u16* qhb = qh + ((size_t)bh*2048 + qb*128)*64;
    const u16* khb = kh + (size_t)bh*2048*64;
    const u16* vtb = vT + (size_t)bh*64*2048;

    // hoist Q fragments (persistent across all k-tiles)
    bf16x8 aq[2][2];
    #pragma unroll
    for (int mi = 0; mi < 2; ++mi)
        #pragma unroll
        for (int kk = 0; kk < 2; ++kk){
            int row = wid*32 + mi*16 + r15;
            aq[mi][kk] = *(const bf16x8*)(qhb + (size_t)row*64 + kk*32 + ch*8);
        }

    f32x4 acc[2][4] = {};

    for (int kt = 0; kt < 16; ++kt){
        #pragma unroll
        for (int kk = 0; kk < 4; ++kk){
            // V fragments for this 32-k slice (B operand, rows = d)
            bf16x8 bv[4];
            #pragma unroll
            for (int nj = 0; nj < 4; ++nj){
                int d = nj*16 + r15;
                bv[nj] = *(const bf16x8*)(vtb + (size_t)d*2048 + kt*128 + kk*32 + ch*8);
            }
            // K fragments (A operand) for the two 16-k tiles of this slice
            bf16x8 bkt[2][2];
            #pragma unroll
            for (int t = 0; t < 2; ++t){
                const u16* krow = khb + (size_t)(kt*128 + (kk*2 + t)*16 + r15)*64;
                bkt[t][0] = *(const bf16x8*)(krow + ch*8);
                bkt[t][1] = *(const bf16x8*)(krow + 32 + ch*8);
            }
            #pragma unroll
            for (int mi = 0; mi < 2; ++mi){
                f32x4 z0 = {}, z1 = {};
                z0 = __builtin_amdgcn_mfma_f32_16x16x32_bf16(bkt[0][0], aq[mi][0], z0, 0,0,0);
                z0 = __builtin_amdgcn_mfma_f32_16x16x32_bf16(bkt[0][1], aq[mi][1], z0, 0,0,0);
                z1 = __builtin_amdgcn_mfma_f32_16x16x32_bf16(bkt[1][0], aq[mi][0], z1, 0,0,0);
                z1 = __builtin_amdgcn_mfma_f32_16x16x32_bf16(bkt[1][1], aq[mi][1], z1, 0,0,0);
                // q pre-scaled by C2 -> exp2 directly; P>0 -> biased-RTZ pack == RNE
                unsigned u0 = pack_bf16_pos_rhu(exp2_hw(z0[0]), exp2_hw(z0[1]));
                unsigned u1 = pack_bf16_pos_rhu(exp2_hw(z0[2]), exp2_hw(z0[3]));
                unsigned w0 = pack_bf16_pos_rhu(exp2_hw(z1[0]), exp2_hw(z1[1]));
                unsigned w1 = pack_bf16_pos_rhu(exp2_hw(z1[2]), exp2_hw(z1[3]));
                plswap32(u0, w0); plswap16(u0, w0);
                plswap32(u1, w1); plswap16(u1, w1);
                union { uint4 ui; bf16x8 v8; } ap;
                ap.ui.x = u0; ap.ui.y = u1; ap.ui.z = w0; ap.ui.w = w1;
                #pragma unroll
                for (int nj = 0; nj < 4; ++nj)
                    acc[mi][nj] = __builtin_amdgcn_mfma_f32_16x16x32_bf16(ap.v8, bv[nj], acc[mi][nj], 0,0,0);
            }
        }
    }

    // epilogue -> merged-head bf16 [b*2048+q][h*64+d]
    const int b = bh >> 4, h = bh & 15;
    #pragma unroll
    for (int mi = 0; mi < 2; ++mi)
        #pragma unroll
        for (int nj = 0; nj < 4; ++nj)
            #pragma unroll
            for (int j = 0; j < 4; ++j){
                int qrow = qb*128 + wid*32 + mi*16 + (lane>>4)*4 + j;
                int d = nj*16 + r15;
                Zbf[((size_t)b*2048 + qrow)*1024 + h*64 + d] = f2bf_rne(acc[mi][nj][j]);
            }
}

extern "C" void kernel_launch(void* const* d_in, const int* in_sizes, int n_in,
                              void* d_out, int out_size, void* d_ws, size_t ws_size,
                              hipStream_t stream)
{
    const float* x  = (const float*)d_in[0];
    const float* Wq = (const float*)d_in[1];
    const float* Wk = (const float*)d_in[2];
    const float* Wv = (const float*)d_in[3];
    const float* Wo = (const float*)d_in[4];

    char* ws = (char*)d_ws;
    u16*   xbf  = (u16*)ws;                       // 16 MB; reused later as Zbf
    u16*   wqkv = (u16*)(ws + (16u<<20));         //  6 MB
    u16*   wobf = (u16*)(ws + (22u<<20));         //  2 MB
    u16*   vT   = (u16*)(ws + (24u<<20));         // 16 MB [64 bh][64 dh][2048 s]
    u16*   Zbf  = xbf;

    u16* qh = (u16*)d_out;                        // 16 MB [64 bh][2048 s][64 dh]
    u16* kh = (u16*)d_out + (size_t)8192*1024;    // 16 MB

    k_cvt<<<1024, 256, 0, stream>>>(x,  xbf,  8192*1024/8);
    k_cvt<<<256,  256, 0, stream>>>(Wq, wqkv,               1024*1024/8);
    k_cvt<<<256,  256, 0, stream>>>(Wk, wqkv + 1024*1024,   1024*1024/8);
    k_cvt<<<256,  256, 0, stream>>>(Wv, wqkv + 2*1024*1024, 1024*1024/8);
    k_cvt<<<256,  256, 0, stream>>>(Wo, wobf,               1024*1024/8);

    // QKV projection (fused): [8192][1024] x [3072][1024]^T
    k_gemm<1><<<dim3(24, 64), 256, 0, stream>>>(xbf, wqkv, nullptr, qh, kh, vT, 1024, 3072);

    // Pass A: per-key denominators + in-place V scaling (grid: bh fastest -> head-per-XCD)
    k_passAV<<<dim3(64, 16), 256, 0, stream>>>(qh, kh, vT);

    // Pass B: fused QK^T -> exp2 -> PV (grid: bh fastest -> head-per-XCD)
    k_passB<<<dim3(64, 16), 256, 0, stream>>>(qh, kh, vT, Zbf);

    // Output projection: [8192][1024] x [1024][1024]^T -> fp32 d_out
    k_gemm<0><<<dim3(8, 64), 256, 0, stream>>>(Zbf, wobf, (float*)d_out,
                                               nullptr, nullptr, nullptr, 1024, 1024);
}